// Round 22
// baseline (67.650 us; speedup 1.0000x reference)
//
#include <hip/hip_runtime.h>

#define EPSV (1e-7f)
#define LN2F (0.69314718055994531f)
#define NEGK (-(1 << 29))   // frame sentinel for empty (value==0) states (warm-up)

constexpr int Tdim = 1024;
constexpr int Kdim = 128;
constexpr int Ldim = 64;
constexpr int BLK  = 32;    // time-steps per LDS block
constexpr int NBUF = 4;     // DMA ring depth (64KB window; 2 WG/CU preserved)
constexpr int WARM = 96;    // warm-up steps (front crosses lattice; verified R18)
constexpr int CENB = 175;   // renorm target biased exponent (lane max ~2^48)

// Async global->LDS DMA, 16B/lane. PER-LANE global source (base + lane*16B),
// wave-uniform LDS dest (m104/m108). One 64-lane call = 1024B = 2 rows.
__device__ __forceinline__ void dma16(const float* g, float* l) {
    __builtin_amdgcn_global_load_lds(
        (const __attribute__((address_space(1))) unsigned int*)g,
        (__attribute__((address_space(3))) unsigned int*)l,
        16, 0, 0);
}

// Wave shift-up-by-1 via DPP (wave_shr:1, ctrl 0x138), proven R14-R21.
// bound_ctrl=false: lane 0 keeps `old`.
__device__ __forceinline__ float dpp_shr1_f(float x, float old) {
    return __int_as_float(__builtin_amdgcn_update_dpp(
        __float_as_int(old), __float_as_int(x), 0x138, 0xF, 0xF, false));
}
__device__ __forceinline__ int dpp_shr1_i(int x, int old) {
    return __builtin_amdgcn_update_dpp(old, x, 0x138, 0xF, 0xF, false);
}

__device__ __forceinline__ float hw_log2(float x) { return __builtin_amdgcn_logf(x); }
__device__ __forceinline__ int imax(int a, int b) { return a > b ? a : b; }

__global__ __launch_bounds__(64, 1) void ctc_fwd_kernel(
    const int* __restrict__ y_true,      // (B, 64)
    const float* __restrict__ y_pred,    // (B, T, K)
    const int* __restrict__ in_len,      // (B, 1)
    const int* __restrict__ lab_len,     // (B, 1)
    float* __restrict__ out)             // (B, 1)
{
    const int b = blockIdx.x;
    const int lane = threadIdx.x;

    __shared__ float rows[NBUF][BLK][Kdim]; // 64 KB: 4-deep DMA ring
    __shared__ float alpha_s[130];
    __shared__ int   ks_s[130];

    const float* yp  = y_pred + (size_t)b * Tdim * Kdim;
    const int lab = y_true[b * Ldim + lane];          // labels 0..126 (never blank)
    const int lab_prev = __shfl_up(lab, 1, 64);       // once, outside hot loop
    const bool skip = (lane > 0) && (lab != Kdim - 1) && (lab != lab_prev);
    const int steps = in_len[b];                      // 512..1024

    // ---- WARM-UP state: per-STATE extended exponent (R15/R17 proven) ----
    float a_e = (lane == 0) ? 1.0f : 0.0f;
    float a_o = 0.0f;
    float a_l = 0.0f;
    int   k_e = (lane == 0) ? 0 : NEGK;
    int   k_o = NEGK;
    int   k_l = NEGK;

    auto issue = [&](int t0, int buf) {
        #pragma unroll
        for (int u = 0; u < BLK / 2; ++u) {
            int t = t0 + 2 * u;
            t = (t > Tdim - 2) ? (Tdim - 2) : t;     // clamp pair: in-bounds
            dma16(yp + (size_t)t * Kdim + 4 * lane, &rows[buf][2 * u][0]);
        }
    };

    // R17 slow step (proven absmax 0): per-state frames + zero-guards.
    auto step_slow = [&](float pl, float pb) {
        const float p_o = dpp_shr1_f(a_o, 0.0f);
        const int   pk  = dpp_shr1_i(k_o, NEGK);
        const int   pk3 = skip ? pk  : NEGK;
        const float p3v = skip ? p_o : 0.0f;
        const int kw1 = imax(k_e, pk);
        const float ne = pb * (ldexpf(a_e, k_e - kw1) + ldexpf(p_o, pk - kw1));
        const int kw2 = imax(imax(k_o, k_e), pk3);
        const float no = pl * (ldexpf(a_o, k_o - kw2) +
                               ldexpf(a_e, k_e - kw2) +
                               ldexpf(p3v, pk3 - kw2));
        const int kw3 = imax(k_l, k_o);
        const float nl = pb * (ldexpf(a_l, k_l - kw3) + ldexpf(a_o, k_o - kw3));
        a_e = ne; k_e = (ne == 0.0f) ? NEGK : kw1;
        a_o = no; k_o = (no == 0.0f) ? NEGK : kw2;
        a_l = nl; k_l = (nl == 0.0f) ? NEGK : kw3;
    };
    auto renorm1 = [](float& v, int& k) {
        const int mb = (__float_as_int(v) >> 23) & 0xff;
        if (mb != 0) { k += mb - 127; v *= __int_as_float((254 - mb) << 23); }
    };
    auto renorm_slow = [&]() { renorm1(a_e, k_e); renorm1(a_o, k_o); renorm1(a_l, k_l); };

    // prologue: fill the 4-deep ring (blocks 0..3, 64 KB in flight)
    issue(0 * BLK, 0);
    issue(1 * BLK, 1);
    issue(2 * BLK, 2);
    issue(3 * BLK, 3);

    const int steps_full = steps & ~(BLK - 1);   // >= 512, multiple of BLK

    // Fence-free refill phasing: at block B (>=1) issue block B+3 into buffer
    // (B+3)%4 == (B-1)%4 — the buffer consumed at block B-1 (its ds_reads
    // completed there: their results fed B-1's steps). So the refill needs NO
    // lgkmcnt fence and overlaps this block's reads + compute.
    // vmcnt audit: issued by B = 16(B+4); vmcnt(48) => landed >= 16(B+1)
    // => block B landed before its reads. (Same guarantee as R21.)

    // ---- warm-up: first WARM steps with the proven slow path ----
    for (int tb = 0; tb < WARM; tb += BLK) {
        const int cur = (tb >> 5) & (NBUF - 1);
        asm volatile("s_waitcnt vmcnt(48)" ::: "memory");
        __builtin_amdgcn_sched_barrier(0);
        if (tb != 0) issue(tb + (NBUF - 1) * BLK, (cur + NBUF - 1) & (NBUF - 1));
        float vl[BLK], vb[BLK];
        #pragma unroll
        for (int u = 0; u < BLK; ++u) {
            vl[u] = rows[cur][u][lab] + EPSV;
            vb[u] = rows[cur][u][Kdim - 1] + EPSV;
        }
        #pragma unroll
        for (int u = 0; u < BLK; ++u) {
            step_slow(vl[u], vb[u]);
            if ((u & 3) == 3) renorm_slow();
        }
    }

    // ---- convert to per-LANE frozen frame, lane max centered at 2^48 ----
    int kk = imax(imax(k_e, k_o), k_l);
    a_e = ldexpf(a_e, k_e - kk + 48);
    a_o = ldexpf(a_o, k_o - kk + 48);
    a_l = ldexpf(a_l, k_l - kk + 48);
    kk -= 48;
    int d = 0;                                 // set by first renorm_fast

    // fast renorm: re-center lane max to [2^48, 2^49), refresh kk and d.
    auto renorm_fast = [&]() {
        const float m = fmaxf(fmaxf(a_e, a_o), a_l);     // > 0, normal range
        const int mb = __float_as_int(m) >> 23;
        const float sc = __int_as_float((127 + CENB - mb) << 23);  // 2^(CENB-mb)
        kk += mb - CENB;
        a_e *= sc; a_o *= sc; a_l *= sc;
        d = dpp_shr1_i(kk, 0) - kk;            // lane0: d unused (p_o=0)
    };
    // fast step: pure f32, frames frozen. ~10 VALU. (R18-proven)
    auto step_fast = [&](float pl, float pb) {
        const float p_o  = dpp_shr1_f(a_o, 0.0f);        // lane0 -> 0
        const float p_a  = ldexpf(p_o, d);               // align neighbor frame
        const float p_s  = skip ? p_a : 0.0f;
        const float ne = pb * (a_e + p_a);
        const float no = pl * (a_o + (a_e + p_s));
        const float nl = pb * (a_l + a_o);
        a_e = ne; a_o = no; a_l = nl;
    };

    // ---- main fast loop ----
    for (int tb = WARM; tb < steps_full; tb += BLK) {
        const int cur = (tb >> 5) & (NBUF - 1);
        asm volatile("s_waitcnt vmcnt(48)" ::: "memory");
        __builtin_amdgcn_sched_barrier(0);
        issue(tb + (NBUF - 1) * BLK, (cur + NBUF - 1) & (NBUF - 1));
        float vl[BLK], vb[BLK];
        #pragma unroll
        for (int u = 0; u < BLK; ++u) {
            vl[u] = rows[cur][u][lab] + EPSV;
            vb[u] = rows[cur][u][Kdim - 1] + EPSV;
        }
        #pragma unroll
        for (int u = 0; u < BLK; ++u) {
            if ((u & 3) == 0) renorm_fast();   // group head: re-center + d
            step_fast(vl[u], vb[u]);
        }
    }

    // ---- tail block (<= 31 steps) + mandatory final DMA drain ----
    {
        const int cur = (steps_full >> 5) & (NBUF - 1);
        asm volatile("s_waitcnt vmcnt(0)" ::: "memory");
        __builtin_amdgcn_sched_barrier(0);
        float vl[BLK], vb[BLK];
        #pragma unroll
        for (int u = 0; u < BLK; ++u) {
            vl[u] = rows[cur][u][lab] + EPSV;
            vb[u] = rows[cur][u][Kdim - 1] + EPSV;
        }
        #pragma unroll
        for (int u = 0; u < BLK; ++u) {
            if (steps_full + u < steps) {      // wave-uniform guard
                if ((u & 3) == 0) renorm_fast();
                step_fast(vl[u], vb[u]);
            }
        }
    }

    alpha_s[2 * lane]     = a_e;
    alpha_s[2 * lane + 1] = a_o;
    ks_s[2 * lane]        = kk;
    ks_s[2 * lane + 1]    = kk;
    if (lane == 63) { alpha_s[128] = a_l; ks_s[128] = kk; }
    __syncthreads();

    if (lane == 0) {
        const int ll = lab_len[b];            // 8..64
        const int i1 = 2 * ll;
        const int i2 = i1 - 1;                // ll >= 8 -> no clamp needed
        const float v1 = alpha_s[i1], v2 = alpha_s[i2];
        const int   k1 = ks_s[i1],   k2 = ks_s[i2];
        const int   K  = imax(k1, k2);
        const float s  = ldexpf(v1, k1 - K) + ldexpf(v2, k2 - K);
        out[b] = -LN2F * (hw_log2(s) + (float)K);
    }
}

extern "C" void kernel_launch(void* const* d_in, const int* in_sizes, int n_in,
                              void* d_out, int out_size, void* d_ws, size_t ws_size,
                              hipStream_t stream) {
    const int*   y_true   = (const int*)d_in[0];
    const float* y_pred   = (const float*)d_in[1];
    const int*   in_len   = (const int*)d_in[2];
    const int*   lab_len  = (const int*)d_in[3];
    float* out = (float*)d_out;

    const int B = in_sizes[0] / Ldim;   // 512
    ctc_fwd_kernel<<<B, 64, 0, stream>>>(y_true, y_pred, in_len, lab_len, out);
}

// Round 23
// 57.674 us; speedup vs baseline: 1.1730x; 1.1730x over previous
//
#include <hip/hip_runtime.h>

#define EPSV (1e-7f)
#define LN2F (0.69314718055994531f)
#define NEGK (-(1 << 29))   // frame sentinel for empty (value==0) states (warm-up)

constexpr int Tdim = 1024;
constexpr int Kdim = 128;
constexpr int Ldim = 64;
constexpr int BLK  = 32;    // time-steps per LDS block
constexpr int NBUF = 4;     // DMA ring depth (64KB = vmcnt-cap window; 2 WG/CU)
constexpr int WARM = 96;    // warm-up steps (front crosses lattice; verified R18)
constexpr int CENB = 188;   // renorm target biased exponent (lane max ~2^61;
                            // supports renorm-every-8 with eps=1e-7: worst-case
                            // 8-step decay 2^-186 -> max >= 2^-125, still normal)

// Async global->LDS DMA, 16B/lane. PER-LANE global source (base + lane*16B),
// wave-uniform LDS dest (m104/m108). One 64-lane call = 1024B = 2 rows.
__device__ __forceinline__ void dma16(const float* g, float* l) {
    __builtin_amdgcn_global_load_lds(
        (const __attribute__((address_space(1))) unsigned int*)g,
        (__attribute__((address_space(3))) unsigned int*)l,
        16, 0, 0);
}

// Wave shift-up-by-1 via DPP (wave_shr:1, ctrl 0x138), proven R14-R21.
// bound_ctrl=false: lane 0 keeps `old`.
__device__ __forceinline__ float dpp_shr1_f(float x, float old) {
    return __int_as_float(__builtin_amdgcn_update_dpp(
        __float_as_int(old), __float_as_int(x), 0x138, 0xF, 0xF, false));
}
__device__ __forceinline__ int dpp_shr1_i(int x, int old) {
    return __builtin_amdgcn_update_dpp(old, x, 0x138, 0xF, 0xF, false);
}

__device__ __forceinline__ float hw_log2(float x) { return __builtin_amdgcn_logf(x); }
__device__ __forceinline__ int imax(int a, int b) { return a > b ? a : b; }

__global__ __launch_bounds__(64, 1) void ctc_fwd_kernel(
    const int* __restrict__ y_true,      // (B, 64)
    const float* __restrict__ y_pred,    // (B, T, K)
    const int* __restrict__ in_len,      // (B, 1)
    const int* __restrict__ lab_len,     // (B, 1)
    float* __restrict__ out)             // (B, 1)
{
    const int b = blockIdx.x;
    const int lane = threadIdx.x;

    __shared__ float rows[NBUF][BLK][Kdim]; // 64 KB: 4-deep DMA ring
    __shared__ float alpha_s[130];
    __shared__ int   ks_s[130];

    const float* yp  = y_pred + (size_t)b * Tdim * Kdim;
    const int lab = y_true[b * Ldim + lane];          // labels 0..126 (never blank)
    const int lab_prev = __shfl_up(lab, 1, 64);       // once, outside hot loop
    const bool skip = (lane > 0) && (lab != Kdim - 1) && (lab != lab_prev);
    const int steps = in_len[b];                      // 512..1024

    // ---- WARM-UP state: per-STATE extended exponent (R15/R17 proven) ----
    float a_e = (lane == 0) ? 1.0f : 0.0f;
    float a_o = 0.0f;
    float a_l = 0.0f;
    int   k_e = (lane == 0) ? 0 : NEGK;
    int   k_o = NEGK;
    int   k_l = NEGK;

    auto issue = [&](int t0, int buf) {
        #pragma unroll
        for (int u = 0; u < BLK / 2; ++u) {
            int t = t0 + 2 * u;
            t = (t > Tdim - 2) ? (Tdim - 2) : t;     // clamp pair: in-bounds
            dma16(yp + (size_t)t * Kdim + 4 * lane, &rows[buf][2 * u][0]);
        }
    };

    // R17 slow step (proven absmax 0): per-state frames + zero-guards.
    auto step_slow = [&](float pl, float pb) {
        const float p_o = dpp_shr1_f(a_o, 0.0f);
        const int   pk  = dpp_shr1_i(k_o, NEGK);
        const int   pk3 = skip ? pk  : NEGK;
        const float p3v = skip ? p_o : 0.0f;
        const int kw1 = imax(k_e, pk);
        const float ne = pb * (ldexpf(a_e, k_e - kw1) + ldexpf(p_o, pk - kw1));
        const int kw2 = imax(imax(k_o, k_e), pk3);
        const float no = pl * (ldexpf(a_o, k_o - kw2) +
                               ldexpf(a_e, k_e - kw2) +
                               ldexpf(p3v, pk3 - kw2));
        const int kw3 = imax(k_l, k_o);
        const float nl = pb * (ldexpf(a_l, k_l - kw3) + ldexpf(a_o, k_o - kw3));
        a_e = ne; k_e = (ne == 0.0f) ? NEGK : kw1;
        a_o = no; k_o = (no == 0.0f) ? NEGK : kw2;
        a_l = nl; k_l = (nl == 0.0f) ? NEGK : kw3;
    };
    auto renorm1 = [](float& v, int& k) {
        const int mb = (__float_as_int(v) >> 23) & 0xff;
        if (mb != 0) { k += mb - 127; v *= __int_as_float((254 - mb) << 23); }
    };
    auto renorm_slow = [&]() { renorm1(a_e, k_e); renorm1(a_o, k_o); renorm1(a_l, k_l); };

    // prologue: fill the 4-deep ring (blocks 0..3, 64 KB in flight)
    issue(0 * BLK, 0);
    issue(1 * BLK, 1);
    issue(2 * BLK, 2);
    issue(3 * BLK, 3);

    const int steps_full = steps & ~(BLK - 1);   // >= 512, multiple of BLK

    // ---- warm-up: first WARM steps with the proven slow path ----
    // R21 schedule (proven best): vmcnt(48) -> reads up-front -> lgkmcnt(0)
    // fence (keeps reads batched, NOT sunk into the chain) -> refill -> steps.
    for (int tb = 0; tb < WARM; tb += BLK) {
        const int cur = (tb >> 5) & (NBUF - 1);
        asm volatile("s_waitcnt vmcnt(48)" ::: "memory");
        __builtin_amdgcn_sched_barrier(0);
        float vl[BLK], vb[BLK];
        #pragma unroll
        for (int u = 0; u < BLK; ++u) {
            vl[u] = rows[cur][u][lab] + EPSV;
            vb[u] = rows[cur][u][Kdim - 1] + EPSV;
        }
        asm volatile("s_waitcnt lgkmcnt(0)" ::: "memory");   // reads done
        __builtin_amdgcn_sched_barrier(0);
        issue(tb + NBUF * BLK, cur);          // refill just-freed buffer
        __builtin_amdgcn_sched_barrier(0);
        #pragma unroll
        for (int u = 0; u < BLK; ++u) {
            step_slow(vl[u], vb[u]);
            if ((u & 3) == 3) renorm_slow();
        }
    }

    // ---- convert to per-LANE frozen frame ----
    int kk = imax(imax(k_e, k_o), k_l);
    a_e = ldexpf(a_e, k_e - kk + 48);
    a_o = ldexpf(a_o, k_o - kk + 48);
    a_l = ldexpf(a_l, k_l - kk + 48);
    kk -= 48;
    int d = 0;                                 // set by first renorm_fast

    // fast renorm: re-center lane max to [2^61, 2^62), refresh kk and d.
    auto renorm_fast = [&]() {
        const float m = fmaxf(fmaxf(a_e, a_o), a_l);     // > 0, normal range
        const int mb = __float_as_int(m) >> 23;
        const float sc = __int_as_float((127 + CENB - mb) << 23);  // 2^(CENB-mb)
        kk += mb - CENB;
        a_e *= sc; a_o *= sc; a_l *= sc;
        d = dpp_shr1_i(kk, 0) - kk;            // lane0: d unused (p_o=0)
    };
    // fast step: pure f32, frames frozen. Chain 5 ops (eo off-chain).
    auto step_fast = [&](float pl, float pb) {
        const float p_o  = dpp_shr1_f(a_o, 0.0f);        // lane0 -> 0
        const float p_a  = ldexpf(p_o, d);               // align neighbor frame
        const float p_s  = skip ? p_a : 0.0f;
        const float eo   = a_o + a_e;                    // off the dpp chain
        const float ne = pb * (a_e + p_a);
        const float no = pl * (eo + p_s);
        const float nl = pb * (a_l + a_o);
        a_e = ne; a_o = no; a_l = nl;
    };

    // ---- main fast loop ----
    for (int tb = WARM; tb < steps_full; tb += BLK) {
        const int cur = (tb >> 5) & (NBUF - 1);
        asm volatile("s_waitcnt vmcnt(48)" ::: "memory");
        __builtin_amdgcn_sched_barrier(0);
        float vl[BLK], vb[BLK];
        #pragma unroll
        for (int u = 0; u < BLK; ++u) {
            vl[u] = rows[cur][u][lab] + EPSV;
            vb[u] = rows[cur][u][Kdim - 1] + EPSV;
        }
        asm volatile("s_waitcnt lgkmcnt(0)" ::: "memory");
        __builtin_amdgcn_sched_barrier(0);
        issue(tb + NBUF * BLK, cur);          // refill just-freed buffer
        __builtin_amdgcn_sched_barrier(0);
        #pragma unroll
        for (int u = 0; u < BLK; ++u) {
            if ((u & 7) == 0) renorm_fast();   // every 8 steps (CENB=188-safe)
            step_fast(vl[u], vb[u]);
        }
    }

    // ---- tail block (<= 31 steps) + mandatory final DMA drain ----
    {
        const int cur = (steps_full >> 5) & (NBUF - 1);
        asm volatile("s_waitcnt vmcnt(0)" ::: "memory");
        __builtin_amdgcn_sched_barrier(0);
        float vl[BLK], vb[BLK];
        #pragma unroll
        for (int u = 0; u < BLK; ++u) {
            vl[u] = rows[cur][u][lab] + EPSV;
            vb[u] = rows[cur][u][Kdim - 1] + EPSV;
        }
        #pragma unroll
        for (int u = 0; u < BLK; ++u) {
            if (steps_full + u < steps) {      // wave-uniform guard
                if ((u & 7) == 0) renorm_fast();
                step_fast(vl[u], vb[u]);
            }
        }
    }

    alpha_s[2 * lane]     = a_e;
    alpha_s[2 * lane + 1] = a_o;
    ks_s[2 * lane]        = kk;
    ks_s[2 * lane + 1]    = kk;
    if (lane == 63) { alpha_s[128] = a_l; ks_s[128] = kk; }
    __syncthreads();

    if (lane == 0) {
        const int ll = lab_len[b];            // 8..64
        const int i1 = 2 * ll;
        const int i2 = i1 - 1;                // ll >= 8 -> no clamp needed
        const float v1 = alpha_s[i1], v2 = alpha_s[i2];
        const int   k1 = ks_s[i1],   k2 = ks_s[i2];
        const int   K  = imax(k1, k2);
        const float s  = ldexpf(v1, k1 - K) + ldexpf(v2, k2 - K);
        out[b] = -LN2F * (hw_log2(s) + (float)K);
    }
}

extern "C" void kernel_launch(void* const* d_in, const int* in_sizes, int n_in,
                              void* d_out, int out_size, void* d_ws, size_t ws_size,
                              hipStream_t stream) {
    const int*   y_true   = (const int*)d_in[0];
    const float* y_pred   = (const float*)d_in[1];
    const int*   in_len   = (const int*)d_in[2];
    const int*   lab_len  = (const int*)d_in[3];
    float* out = (float*)d_out;

    const int B = in_sizes[0] / Ldim;   // 512
    ctc_fwd_kernel<<<B, 64, 0, stream>>>(y_true, y_pred, in_len, lab_len, out);
}